// Round 1
// baseline (69.413 us; speedup 1.0000x reference)
//
#include <hip/hip_runtime.h>

#define BB 1024
#define SS 256
#define VV 256
#define HH 10
#define GG 40   // 4*H
#define LL 15

__device__ __forceinline__ float fexp2(float x) {
#if __has_builtin(__builtin_amdgcn_exp2f)
    return __builtin_amdgcn_exp2f(x);
#else
    return exp2f(x);
#endif
}
__device__ __forceinline__ float frcp(float x) {
#if __has_builtin(__builtin_amdgcn_rcpf)
    return __builtin_amdgcn_rcpf(x);
#else
    return 1.0f / x;
#endif
}
__device__ __forceinline__ float bcast_lane(float v, int srcLane) {
#if __has_builtin(__builtin_amdgcn_readlane)
    return __int_as_float(__builtin_amdgcn_readlane(__float_as_int(v), srcLane));
#else
    return __shfl(v, srcLane, 64);
#endif
}

// One wave per batch element. Lane j (<40) owns gate j:
//   j in [0,10): i   [10,20): f   [20,30): g(tanh)   [30,40): o
// Lane j keeps Wh[:,j] in 10 VGPRs; h is broadcast as wave-uniform values
// via v_readlane each step. Cell state c_k is maintained redundantly by all
// lanes with k = j % 10 (removes a second shuffle round).
__global__ __launch_bounds__(256) void charrnn_lstm_kernel(
    const int*   __restrict__ x,     // [B,S]
    const float* __restrict__ Wx,    // [V,4H]
    const float* __restrict__ Wh,    // [H,4H]
    const float* __restrict__ bias,  // [4H]
    const float* __restrict__ Wd,    // [H,L]
    const float* __restrict__ bd,    // [L]
    const float* __restrict__ dropr, // [1]
    float*       __restrict__ out)   // [B,L]
{
    __shared__ int xs[4 * SS];       // this block's 4 batch rows of x

    const int tid  = threadIdx.x;
    const int wave = tid >> 6;
    const int lane = tid & 63;
    const int batch = blockIdx.x * 4 + wave;

    // Stage the block's 4 contiguous x rows into LDS (coalesced).
    {
        const int* xsrc = x + (size_t)blockIdx.x * 4 * SS;
        #pragma unroll
        for (int i = 0; i < 4; ++i) xs[tid + i * 256] = xsrc[tid + i * 256];
    }
    __syncthreads();

    const int j = (lane < GG) ? lane : 0;   // gate index (idle lanes mirror lane 0)
    const int k = j % HH;                   // hidden unit this lane's gate feeds

    // Per-lane recurrent weights: Wh[:, j]
    float wh[HH];
    #pragma unroll
    for (int kk = 0; kk < HH; ++kk) wh[kk] = Wh[kk * GG + j];
    const float bj = bias[j];

    // Unified activation: act = aa * rcp(1 + exp2(m*g)) + cc
    //  sigmoid: m=-log2e, aa=1, cc=0 ; tanh: m=-2log2e, aa=2, cc=-1
    const float LOG2E = 1.4426950408889634f;
    const bool isTanh = (j >= 2 * HH) && (j < 3 * HH);
    const float m  = isTanh ? (-2.0f * LOG2E) : (-LOG2E);
    const float aa = isTanh ? 2.0f : 1.0f;
    const float cc = isTanh ? -1.0f : 0.0f;

    const int* xrow = xs + wave * SS;

    float hk[HH];                     // wave-uniform h broadcast values
    #pragma unroll
    for (int kk = 0; kk < HH; ++kk) hk[kk] = 0.0f;
    float cstate = 0.0f;

    // 2-deep prefetch of Wx rows (indices known ahead of time)
    float wxA = Wx[xrow[0] * GG + j];
    float wxB = Wx[xrow[1] * GG + j];

    #pragma unroll 1
    for (int s = 0; s < SS; ++s) {
        // gate pre-activation: 10-FMA chain with SGPR h operands
        float g = wxA + bj;
        #pragma unroll
        for (int kk = 0; kk < HH; ++kk) g = fmaf(hk[kk], wh[kk], g);

        // rotate prefetch pipeline (load for step s+2)
        wxA = wxB;
        const int sn = (s + 2 < SS) ? (s + 2) : (SS - 1);
        wxB = Wx[xrow[sn] * GG + j];

        // activation (divergence-free)
        const float e   = fexp2(g * m);
        const float r   = frcp(1.0f + e);
        const float act = fmaf(aa, r, cc);

        // gather the 4 gates of hidden unit k (4 bpermutes, latencies overlap)
        const float iv = __shfl(act, k, 64);
        const float fv = __shfl(act, k + HH, 64);
        const float gv = __shfl(act, k + 2 * HH, 64);
        const float ov = __shfl(act, k + 3 * HH, 64);

        // cell + hidden update (redundant across the 4 lanes sharing k)
        cstate = fmaf(fv, cstate, iv * gv);
        const float e2 = fexp2(cstate * (-2.0f * LOG2E));
        const float th = fmaf(2.0f, frcp(1.0f + e2), -1.0f);
        const float hv = ov * th;

        // broadcast h_0..h_9 from lanes 0..9 into wave-uniform registers
        #pragma unroll
        for (int kk = 0; kk < HH; ++kk) hk[kk] = bcast_lane(hv, kk);
    }

    // dropout (rate is an input; 0 here -> scale 1) + dense head on lanes < 15
    const float scale = 1.0f / (1.0f - dropr[0]);
    const int l = (lane < LL) ? lane : 0;
    float acc = bd[l];
    #pragma unroll
    for (int kk = 0; kk < HH; ++kk)
        acc = fmaf(hk[kk] * scale, Wd[kk * LL + l], acc);
    if (lane < LL) out[(size_t)batch * LL + lane] = acc;
}

extern "C" void kernel_launch(void* const* d_in, const int* in_sizes, int n_in,
                              void* d_out, int out_size, void* d_ws, size_t ws_size,
                              hipStream_t stream) {
    const int*   x     = (const int*)d_in[0];
    const float* Wx    = (const float*)d_in[1];
    const float* Wh    = (const float*)d_in[2];
    const float* b     = (const float*)d_in[3];
    const float* Wd    = (const float*)d_in[4];
    const float* bd    = (const float*)d_in[5];
    const float* dropr = (const float*)d_in[6];
    float* out = (float*)d_out;

    dim3 grid(BB / 4);   // 256 blocks: 4 waves each -> 1024 waves, 1/SIMD chip-wide
    dim3 block(256);
    charrnn_lstm_kernel<<<grid, block, 0, stream>>>(x, Wx, Wh, b, Wd, bd, dropr, out);
}

// Round 2
// 48.832 us; speedup vs baseline: 1.4215x; 1.4215x over previous
//
#include <hip/hip_runtime.h>

#define BB 1024
#define SS 256
#define VV 256
#define HH 10
#define GG 40   // 4*H
#define LL 15

__device__ __forceinline__ float fexp2(float x) {
#if __has_builtin(__builtin_amdgcn_exp2f)
    return __builtin_amdgcn_exp2f(x);
#else
    return exp2f(x);
#endif
}
__device__ __forceinline__ float frcp(float x) {
#if __has_builtin(__builtin_amdgcn_rcpf)
    return __builtin_amdgcn_rcpf(x);
#else
    return 1.0f / x;
#endif
}
__device__ __forceinline__ float rdlane(float v, int srcLane) {
#if __has_builtin(__builtin_amdgcn_readlane)
    return __int_as_float(__builtin_amdgcn_readlane(__float_as_int(v), srcLane));
#else
    return __shfl(v, srcLane, 64);
#endif
}

// quad_perm broadcast of lane t within each 4-lane quad: CTRL = t*0x55.
template<int CTRL>
__device__ __forceinline__ float dpp_qbcast(float v) {
#if __has_builtin(__builtin_amdgcn_mov_dpp)
    return __int_as_float(__builtin_amdgcn_mov_dpp(__float_as_int(v), CTRL, 0xF, 0xF, true));
#else
    return __shfl(v, (threadIdx.x & 60) + (CTRL & 3), 64);
#endif
}

// One wave per batch element. Lane layout: lane = 4*k + t, k<10 hidden unit,
// t in {0:i, 1:f, 2:g(tanh), 3:o}. The i/f/g/o of unit k live in one lane
// quad -> gate gather is 4 DPP quad_perm broadcasts (VALU latency) instead of
// ds_bpermute (~120cy + lgkm drain). Activation slope m and bias are folded
// into the weights so the chain is: 2x5-FMA || add -> exp2 -> rcp -> fma ->
// DPP x4 -> fma(c) -> mul -> exp2 -> rcp -> fma(h) -> readlane x10.
__global__ __launch_bounds__(256) void charrnn_lstm_kernel(
    const int*   __restrict__ x,     // [B,S]
    const float* __restrict__ Wx,    // [V,4H]
    const float* __restrict__ Wh,    // [H,4H]
    const float* __restrict__ bias,  // [4H]
    const float* __restrict__ Wd,    // [H,L]
    const float* __restrict__ bd,    // [L]
    const float* __restrict__ dropr, // [1]
    float*       __restrict__ out)   // [B,L]
{
    __shared__ int xs[4 * SS];       // this block's 4 batch rows of x

    const int tid  = threadIdx.x;
    const int wave = tid >> 6;
    const int lane = tid & 63;
    const int batch = blockIdx.x * 4 + wave;

    {   // stage the block's 4 contiguous x rows into LDS (coalesced)
        const int* xsrc = x + (size_t)blockIdx.x * 4 * SS;
        #pragma unroll
        for (int i = 0; i < 4; ++i) xs[tid + i * 256] = xsrc[tid + i * 256];
    }
    __syncthreads();

    int k = lane >> 2;               // hidden unit
    int t = lane & 3;                // gate type
    if (lane >= GG) { k = 0; t = 0; }  // idle lanes mirror (k=0,t=0); harmless
    const int jg = t * HH + k;       // column in [i(10) f(10) g(10) o(10)]

    const float LOG2E = 1.4426950408889634f;
    const bool  isTanh = (t == 2);
    const float m  = isTanh ? (-2.0f * LOG2E) : (-LOG2E);
    const float aa = isTanh ? 2.0f : 1.0f;
    const float cc = isTanh ? -1.0f : 0.0f;
    const float K2 = -2.0f * LOG2E;  // tanh(c) slope

    // Per-lane recurrent weights with slope folded: m * Wh[:, jg]
    float whm[HH];
    #pragma unroll
    for (int kk = 0; kk < HH; ++kk) whm[kk] = Wh[kk * GG + jg] * m;
    const float bjm = bias[jg] * m;

    const int* xrow = xs + wave * SS;
    auto xat = [&](int s) { return xrow[s < SS ? s : SS - 1]; };

    float hs[HH];                    // wave-uniform h broadcast values
    #pragma unroll
    for (int kk = 0; kk < HH; ++kk) hs[kk] = 0.0f;
    float cstate = 0.0f;

    // Wx pipeline: w0m/w1m/w2m hold m*Wx+bjm for steps s, s+1, s+2.
    // rawP/rawPP hold raw loads for steps s+3, s+4 (mul deferred 2 iters so
    // vmcnt wait has ~2 iterations of slack). idxU/idxN feed the next loads.
    float w0m  = fmaf(Wx[xat(0) * GG + jg], m, bjm);
    float w1m  = fmaf(Wx[xat(1) * GG + jg], m, bjm);
    float w2m  = fmaf(Wx[xat(2) * GG + jg], m, bjm);
    float rawP  = Wx[xat(3) * GG + jg];
    float rawPP = Wx[xat(4) * GG + jg];
    int   idxU  = xat(5);
    int   idxN  = xat(6);

    #pragma unroll 1
    for (int s = 0; s < SS; ++s) {
        // gate pre-activation (already scaled by m, bias included in w0m)
        float gA = w0m;
        #pragma unroll
        for (int kk = 0; kk < 5; ++kk) gA = fmaf(hs[kk], whm[kk], gA);
        float gB = hs[5] * whm[5];
        #pragma unroll
        for (int kk = 6; kk < HH; ++kk) gB = fmaf(hs[kk], whm[kk], gB);
        const float gm = gA + gB;

        // prefetch for step s+5 (off critical path)
        const float rawNew = Wx[idxU * GG + jg];
        idxU = idxN;
        idxN = xat(s + 7);

        // unified activation: act = aa*rcp(1+exp2(gm)) + cc
        const float e   = fexp2(gm);
        const float r   = frcp(1.0f + e);
        const float act = fmaf(aa, r, cc);

        // gather this quad's 4 gates via DPP quad_perm broadcasts
        const float iv = dpp_qbcast<0x00>(act);
        const float fv = dpp_qbcast<0x55>(act);
        const float gv = dpp_qbcast<0xAA>(act);
        const float ov = dpp_qbcast<0xFF>(act);

        const float o2 = ov + ov;    // computed during exp2/rcp latency
        const float on = -ov;

        cstate = fmaf(fv, cstate, iv * gv);
        const float e2 = fexp2(cstate * K2);
        const float r2 = frcp(1.0f + e2);
        const float hv = fmaf(o2, r2, on);   // h = o * tanh(c)

        // broadcast h_0..h_9 from lanes 0,4,...,36
        #pragma unroll
        for (int kk = 0; kk < HH; ++kk) hs[kk] = rdlane(hv, 4 * kk);

        // rotate Wx pipeline (vmcnt/mul off the chain)
        w0m = w1m; w1m = w2m;
        w2m = fmaf(rawP, m, bjm);
        rawP = rawPP; rawPP = rawNew;
    }

    // dropout scale (rate=0 -> 1) + dense head on lanes < 15
    const float scale = 1.0f / (1.0f - dropr[0]);
    const int l = (lane < LL) ? lane : 0;
    float acc = bd[l];
    #pragma unroll
    for (int kk = 0; kk < HH; ++kk)
        acc = fmaf(hs[kk] * scale, Wd[kk * LL + l], acc);
    if (lane < LL) out[(size_t)batch * LL + lane] = acc;
}

extern "C" void kernel_launch(void* const* d_in, const int* in_sizes, int n_in,
                              void* d_out, int out_size, void* d_ws, size_t ws_size,
                              hipStream_t stream) {
    const int*   x     = (const int*)d_in[0];
    const float* Wx    = (const float*)d_in[1];
    const float* Wh    = (const float*)d_in[2];
    const float* b     = (const float*)d_in[3];
    const float* Wd    = (const float*)d_in[4];
    const float* bd    = (const float*)d_in[5];
    const float* dropr = (const float*)d_in[6];
    float* out = (float*)d_out;

    dim3 grid(BB / 4);   // 256 blocks x 4 waves = 1024 waves, 1/SIMD chip-wide
    dim3 block(256);
    charrnn_lstm_kernel<<<grid, block, 0, stream>>>(x, Wx, Wh, b, Wd, bd, dropr, out);
}

// Round 3
// 33.164 us; speedup vs baseline: 2.0930x; 1.4724x over previous
//
#include <hip/hip_runtime.h>

#define BB 1024
#define SS 256
#define VV 256
#define HH 10
#define GG 40   // 4*H
#define LL 15

__device__ __forceinline__ float fexp2(float x) {
#if __has_builtin(__builtin_amdgcn_exp2f)
    return __builtin_amdgcn_exp2f(x);
#else
    return exp2f(x);
#endif
}
__device__ __forceinline__ float frcp(float x) {
#if __has_builtin(__builtin_amdgcn_rcpf)
    return __builtin_amdgcn_rcpf(x);
#else
    return 1.0f / x;
#endif
}
__device__ __forceinline__ float rdlane_f(float v, int srcLane) {
#if __has_builtin(__builtin_amdgcn_readlane)
    return __int_as_float(__builtin_amdgcn_readlane(__float_as_int(v), srcLane));
#else
    return __shfl(v, srcLane, 64);
#endif
}
__device__ __forceinline__ int rdlane_i(int v, int srcLane) {
#if __has_builtin(__builtin_amdgcn_readlane)
    return __builtin_amdgcn_readlane(v, srcLane);
#else
    return __shfl(v, srcLane, 64);
#endif
}

// quad_perm broadcast of quad-lane t: CTRL = t*0x55.
template<int CTRL>
__device__ __forceinline__ float dpp_qbcast(float v) {
#if __has_builtin(__builtin_amdgcn_mov_dpp)
    return __int_as_float(__builtin_amdgcn_mov_dpp(__float_as_int(v), CTRL, 0xF, 0xF, true));
#else
    return __shfl(v, (threadIdx.x & 60) + (CTRL & 3), 64);
#endif
}

// One wave per batch element. Lane = 4*k + t; t in {0:i,1:f,2:g,3:o}.
// In-loop memory is ONLY the Wx prefetch load (2-iteration vmcnt slack).
// x indices come from VGPR-resident rows via dynamic v_readlane (uniform
// lane select) -> index lands in SGPR, Wx address math is SALU.
__global__ __launch_bounds__(256) void charrnn_lstm_kernel(
    const int*   __restrict__ x,     // [B,S]
    const float* __restrict__ Wx,    // [V,4H]
    const float* __restrict__ Wh,    // [H,4H]
    const float* __restrict__ bias,  // [4H]
    const float* __restrict__ Wd,    // [H,L]
    const float* __restrict__ bd,    // [L]
    const float* __restrict__ dropr, // [1]
    float*       __restrict__ out)   // [B,L]
{
    const int tid  = threadIdx.x;
    const int wave = tid >> 6;
    const int lane = tid & 63;
    const int batch = blockIdx.x * 4 + wave;

    int k = lane >> 2;               // hidden unit
    int t = lane & 3;                // gate type
    if (lane >= GG) { k = 0; t = 0; }  // idle lanes mirror; bounded, never read
    const int jg = t * HH + k;       // column in [i(10) f(10) g(10) o(10)]

    // x row into registers: xq0[lane]=x[lane]; xsh[r][lane]=x[min(64r+lane+4,255)]
    const int* xrow = x + (size_t)batch * SS;
    const int xq0 = xrow[lane];
    int xsh[4];
    #pragma unroll
    for (int r = 0; r < 4; ++r) {
        int p = 64 * r + lane + 4;
        xsh[r] = xrow[p > SS - 1 ? SS - 1 : p];
    }

    const float LOG2E = 1.4426950408889634f;
    const bool  isTanh = (t == 2);
    const float m  = isTanh ? (-2.0f * LOG2E) : (-LOG2E);
    const float aa = isTanh ? 2.0f : 1.0f;
    const float cc = isTanh ? -1.0f : 0.0f;
    const float K2 = -2.0f * LOG2E;  // tanh(c) slope

    // Per-lane recurrent weights with activation slope folded in
    float whm[HH];
    #pragma unroll
    for (int kk = 0; kk < HH; ++kk) whm[kk] = Wh[kk * GG + jg] * m;
    const float bjm = bias[jg] * m;

    // Pipeline prologue: w0m=W(0), w1m=W(1), rawP=raw(2), rawPP=raw(3)
    const int i0 = rdlane_i(xq0, 0);
    const int i1 = rdlane_i(xq0, 1);
    const int i2 = rdlane_i(xq0, 2);
    const int i3 = rdlane_i(xq0, 3);
    float w0m  = fmaf(Wx[i0 * GG + jg], m, bjm);
    float w1m  = fmaf(Wx[i1 * GG + jg], m, bjm);
    float rawP  = Wx[i2 * GG + jg];
    float rawPP = Wx[i3 * GG + jg];

    float hs[HH];
    #pragma unroll
    for (int kk = 0; kk < HH; ++kk) hs[kk] = 0.0f;
    float cstate = 0.0f;

    #pragma unroll
    for (int r = 0; r < 4; ++r) {
        const int xs_r = xsh[r];
        #pragma unroll 4
        for (int i = 0; i < 64; ++i) {
            // ---- gate pre-activation: 3-way split dot (5 dep levels) ----
            float gA = fmaf(hs[0], whm[0], fmaf(hs[1], whm[1], fmaf(hs[2], whm[2], w0m)));
            float gB = fmaf(hs[3], whm[3], fmaf(hs[4], whm[4], hs[5] * whm[5]));
            float gC = fmaf(hs[6], whm[6], fmaf(hs[7], whm[7], fmaf(hs[8], whm[8], hs[9] * whm[9])));
            const float gm = (gA + gB) + gC;

            // ---- prefetch Wx for step s+4 (index via readlane, SGPR addr) ----
            const int idxn = rdlane_i(xs_r, i);
            const float rawNew = Wx[idxn * GG + jg];

            // ---- unified activation ----
            const float e   = fexp2(gm);
            const float r1  = frcp(1.0f + e);
            const float act = fmaf(aa, r1, cc);

            // o-gate is local on lane 4k+3 (off-chain prep)
            const float o2 = act + act;
            const float on = -act;

            // gather i,f,g via DPP quad broadcasts (all quad lanes get same)
            const float iv = dpp_qbcast<0x00>(act);
            const float fv = dpp_qbcast<0x55>(act);
            const float gv = dpp_qbcast<0xAA>(act);

            // cell update (correct in all quad lanes) + h on lane 4k+3
            cstate = fmaf(fv, cstate, iv * gv);
            const float e2 = fexp2(cstate * K2);
            const float r2 = frcp(1.0f + e2);
            const float hv = fmaf(o2, r2, on);   // o * tanh(c), valid on t==3

            // broadcast h_0..h_9 from lanes 3,7,...,39
            #pragma unroll
            for (int kk = 0; kk < HH; ++kk) hs[kk] = rdlane_f(hv, 4 * kk + 3);

            // rotate Wx pipeline
            w0m = w1m;
            w1m = fmaf(rawP, m, bjm);
            rawP = rawPP;
            rawPP = rawNew;
        }
    }

    // dropout scale (rate=0 -> 1) + dense head on lanes < 15
    const float scale = 1.0f / (1.0f - dropr[0]);
    const int l = (lane < LL) ? lane : 0;
    float acc = bd[l];
    #pragma unroll
    for (int kk = 0; kk < HH; ++kk)
        acc = fmaf(hs[kk] * scale, Wd[kk * LL + l], acc);
    if (lane < LL) out[(size_t)batch * LL + lane] = acc;
}

extern "C" void kernel_launch(void* const* d_in, const int* in_sizes, int n_in,
                              void* d_out, int out_size, void* d_ws, size_t ws_size,
                              hipStream_t stream) {
    const int*   x     = (const int*)d_in[0];
    const float* Wx    = (const float*)d_in[1];
    const float* Wh    = (const float*)d_in[2];
    const float* b     = (const float*)d_in[3];
    const float* Wd    = (const float*)d_in[4];
    const float* bd    = (const float*)d_in[5];
    const float* dropr = (const float*)d_in[6];
    float* out = (float*)d_out;

    dim3 grid(BB / 4);   // 256 blocks x 4 waves = 1024 waves, 1/SIMD chip-wide
    dim3 block(256);
    charrnn_lstm_kernel<<<grid, block, 0, stream>>>(x, Wx, Wh, b, Wd, bd, dropr, out);
}

// Round 4
// 32.780 us; speedup vs baseline: 2.1175x; 1.0117x over previous
//
#include <hip/hip_runtime.h>

#define BB 1024
#define SS 256
#define VV 256
#define HH 10
#define GG 40   // 4*H
#define LL 15

__device__ __forceinline__ float fexp2(float x) {
#if __has_builtin(__builtin_amdgcn_exp2f)
    return __builtin_amdgcn_exp2f(x);
#else
    return exp2f(x);
#endif
}
__device__ __forceinline__ float frcp(float x) {
#if __has_builtin(__builtin_amdgcn_rcpf)
    return __builtin_amdgcn_rcpf(x);
#else
    return 1.0f / x;
#endif
}
__device__ __forceinline__ float rdlane_f(float v, int srcLane) {
#if __has_builtin(__builtin_amdgcn_readlane)
    return __int_as_float(__builtin_amdgcn_readlane(__float_as_int(v), srcLane));
#else
    return __shfl(v, srcLane, 64);
#endif
}
__device__ __forceinline__ int rdlane_i(int v, int srcLane) {
#if __has_builtin(__builtin_amdgcn_readlane)
    return __builtin_amdgcn_readlane(v, srcLane);
#else
    return __shfl(v, srcLane, 64);
#endif
}

// quad_perm broadcast of quad-lane t: CTRL = t*0x55.
template<int CTRL>
__device__ __forceinline__ float dpp_qbcast(float v) {
#if __has_builtin(__builtin_amdgcn_mov_dpp)
    return __int_as_float(__builtin_amdgcn_mov_dpp(__float_as_int(v), CTRL, 0xF, 0xF, true));
#else
    return __shfl(v, (threadIdx.x & 60) + (CTRL & 3), 64);
#endif
}

// One wave per batch element. Lane = 4*k + t; t in {0:i,1:f,2:g,3:o}.
// In-loop memory is ONLY the Wx prefetch load, issued 6 steps ahead
// (folded at +3, consumed at +6) so vmcnt slack ~3 iterations covers
// L2-miss latency (~200cy). x indices come from VGPR-resident rows via
// dynamic v_readlane -> SGPR index -> SALU address math.
__global__ __launch_bounds__(256, 1) void charrnn_lstm_kernel(
    const int*   __restrict__ x,     // [B,S]
    const float* __restrict__ Wx,    // [V,4H]
    const float* __restrict__ Wh,    // [H,4H]
    const float* __restrict__ bias,  // [4H]
    const float* __restrict__ Wd,    // [H,L]
    const float* __restrict__ bd,    // [L]
    const float* __restrict__ dropr, // [1]
    float*       __restrict__ out)   // [B,L]
{
    const int tid  = threadIdx.x;
    const int wave = tid >> 6;
    const int lane = tid & 63;
    const int batch = blockIdx.x * 4 + wave;

    int k = lane >> 2;               // hidden unit
    int t = lane & 3;                // gate type
    if (lane >= GG) { k = 0; t = 0; }  // idle lanes mirror; never sourced
    const int jg = t * HH + k;       // column in [i(10) f(10) g(10) o(10)]

    // x row into registers: xq0[lane]=x[lane]; xsh[r][lane]=x[min(64r+lane+6,255)]
    const int* xrow = x + (size_t)batch * SS;
    const int xq0 = xrow[lane];
    int xsh[4];
    #pragma unroll
    for (int r = 0; r < 4; ++r) {
        int p = 64 * r + lane + 6;
        xsh[r] = xrow[p > SS - 1 ? SS - 1 : p];
    }

    const float LOG2E = 1.4426950408889634f;
    const bool  isTanh = (t == 2);
    const float m  = isTanh ? (-2.0f * LOG2E) : (-LOG2E);
    const float aa = isTanh ? 2.0f : 1.0f;
    const float cc = isTanh ? -1.0f : 0.0f;
    const float K2 = -2.0f * LOG2E;  // tanh(c) slope

    // Per-lane recurrent weights with activation slope folded in
    float whm[HH];
    #pragma unroll
    for (int kk = 0; kk < HH; ++kk) whm[kk] = Wh[kk * GG + jg] * m;
    const float bjm = bias[jg] * m;

    // 6-deep pipeline prologue: w0m..w2m folded for steps 0..2,
    // r3..r5 raw for steps 3..5.
    const int i0 = rdlane_i(xq0, 0);
    const int i1 = rdlane_i(xq0, 1);
    const int i2 = rdlane_i(xq0, 2);
    const int i3 = rdlane_i(xq0, 3);
    const int i4 = rdlane_i(xq0, 4);
    const int i5 = rdlane_i(xq0, 5);
    float w0m = fmaf(Wx[i0 * GG + jg], m, bjm);
    float w1m = fmaf(Wx[i1 * GG + jg], m, bjm);
    float w2m = fmaf(Wx[i2 * GG + jg], m, bjm);
    float r3  = Wx[i3 * GG + jg];
    float r4  = Wx[i4 * GG + jg];
    float r5  = Wx[i5 * GG + jg];

    float hs[HH];
    #pragma unroll
    for (int kk = 0; kk < HH; ++kk) hs[kk] = 0.0f;
    float cstate = 0.0f;

    #pragma unroll
    for (int r = 0; r < 4; ++r) {
        const int xs_r = xsh[r];
        #pragma unroll 8
        for (int i = 0; i < 64; ++i) {
            // ---- gate pre-activation: 3-way split dot ----
            // earliest-arriving hs at the innermost (first-executed) slots
            float gA = fmaf(hs[2], whm[2], fmaf(hs[1], whm[1], fmaf(hs[0], whm[0], w0m)));
            float gB = fmaf(hs[5], whm[5], fmaf(hs[4], whm[4], hs[3] * whm[3]));
            float gC = fmaf(hs[9], whm[9], fmaf(hs[8], whm[8], fmaf(hs[7], whm[7], hs[6] * whm[6])));
            const float gm = gC + (gA + gB);

            // ---- prefetch Wx for step s+6 (SGPR index/address) ----
            const int idxn = rdlane_i(xs_r, i);
            const float rawNew = Wx[idxn * GG + jg];

            // ---- unified activation: act = aa*rcp(1+exp2(gm)) + cc ----
            const float e   = fexp2(gm);
            const float r1  = frcp(1.0f + e);
            const float act = fmaf(aa, r1, cc);

            // o-gate is local on lane 4k+3 (prep overlaps DPP)
            const float o2 = act + act;
            const float on = -act;

            // gather i,f,g via DPP quad broadcasts
            const float iv = dpp_qbcast<0x00>(act);
            const float fv = dpp_qbcast<0x55>(act);
            const float gv = dpp_qbcast<0xAA>(act);

            // cell update (redundant in quad) + h on lane 4k+3
            cstate = fmaf(fv, cstate, iv * gv);
            const float e2 = fexp2(cstate * K2);
            const float r2 = frcp(1.0f + e2);
            const float hv = fmaf(o2, r2, on);   // o * tanh(c), valid on t==3

            // broadcast h_0..h_9 from lanes 3,7,...,39 (hs[0] first)
            #pragma unroll
            for (int kk = 0; kk < HH; ++kk) hs[kk] = rdlane_f(hv, 4 * kk + 3);

            // rotate 6-deep Wx pipeline
            w0m = w1m;
            w1m = w2m;
            w2m = fmaf(r3, m, bjm);
            r3 = r4;
            r4 = r5;
            r5 = rawNew;
        }
    }

    // dropout scale (rate=0 -> 1) + dense head on lanes < 15
    const float scale = 1.0f / (1.0f - dropr[0]);
    const int l = (lane < LL) ? lane : 0;
    float acc = bd[l];
    #pragma unroll
    for (int kk = 0; kk < HH; ++kk)
        acc = fmaf(hs[kk] * scale, Wd[kk * LL + l], acc);
    if (lane < LL) out[(size_t)batch * LL + lane] = acc;
}

extern "C" void kernel_launch(void* const* d_in, const int* in_sizes, int n_in,
                              void* d_out, int out_size, void* d_ws, size_t ws_size,
                              hipStream_t stream) {
    const int*   x     = (const int*)d_in[0];
    const float* Wx    = (const float*)d_in[1];
    const float* Wh    = (const float*)d_in[2];
    const float* b     = (const float*)d_in[3];
    const float* Wd    = (const float*)d_in[4];
    const float* bd    = (const float*)d_in[5];
    const float* dropr = (const float*)d_in[6];
    float* out = (float*)d_out;

    dim3 grid(BB / 4);   // 256 blocks x 4 waves = 1024 waves, 1/SIMD chip-wide
    dim3 block(256);
    charrnn_lstm_kernel<<<grid, block, 0, stream>>>(x, Wx, Wh, b, Wd, bd, dropr, out);
}